// Round 11
// baseline (295.607 us; speedup 1.0000x reference)
//
#include <hip/hip_runtime.h>

#define N_NODES 50000
#define ELLW 48           // ELL width; P(deg>48) ~ 1e-11 total for Poisson(16)

typedef unsigned int uint;
typedef unsigned short ushort;
typedef float floatx4 __attribute__((ext_vector_type(4)));
typedef short short8 __attribute__((ext_vector_type(8)));

__device__ inline ushort f2bf(float f) {
    uint u = __float_as_uint(f);
    return (ushort)((u + 0x7fffu + ((u >> 16) & 1u)) >> 16);
}
__device__ inline float bflo(uint u) { return __uint_as_float(u << 16); }
__device__ inline float bfhi(uint u) { return __uint_as_float(u & 0xffff0000u); }
__device__ inline uint pack2(float lo, float hi) {
    return (uint)f2bf(lo) | ((uint)f2bf(hi) << 16);
}

// ---------------- weight swizzle (MFMA B-frag order) ----------------
__device__ inline void swz_body(const float* __restrict__ W, ushort* __restrict__ Wz,
                                int O, int t) {
    int lane = t & 63, cb = t >> 6;
    int NBm = O / 16;
    int c = cb / NBm, nb = cb % NBm;
    int quad = lane >> 4, l16 = lane & 15;
#pragma unroll
    for (int j = 0; j < 8; j++) {
        float v = W[(size_t)(c * 32 + quad * 8 + j) * O + nb * 16 + l16];
        Wz[(size_t)t * 8 + j] = f2bf(v);
    }
}

// ---------------- K1 GEMM: x_p = relu(x@Wp+bp), y1 = x@Wl1, r1 = x@Wr1 ----------
// One A-tile (64x64 of x, bf16 in LDS), three inline-swizzled B matrices.
__device__ void gemm1_body(int gb, const float* __restrict__ x,
                           const float* __restrict__ Wp, const float* __restrict__ bp,
                           const float* __restrict__ Wl1, const float* __restrict__ Wr1,
                           ushort* __restrict__ feats, ushort* __restrict__ g1in,
                           ushort* __restrict__ r1, ushort* ldsA) {
    constexpr int LDA = 40;
    const int tid = threadIdx.x;
    const int wave = tid >> 6, lane = tid & 63;
    const int quad = lane >> 4, l16 = lane & 15;
    const int node0 = gb * 64;

    floatx4 aP[4], aY[4], aR[4];
#pragma unroll
    for (int nb = 0; nb < 4; nb++) {
        aP[nb] = (floatx4){0, 0, 0, 0};
        aY[nb] = (floatx4){0, 0, 0, 0};
        aR[nb] = (floatx4){0, 0, 0, 0};
    }

#pragma unroll
    for (int kk = 0; kk < 2; kk++) {
        const int k0 = kk * 32;
        __syncthreads();
        {
            int row = tid >> 2, seg = tid & 3;
            int node = node0 + row;
            float4 v0 = {0, 0, 0, 0}, v1 = {0, 0, 0, 0};
            if (node < N_NODES) {
                v0 = *(const float4*)&x[(size_t)node * 64 + k0 + seg * 8];
                v1 = *(const float4*)&x[(size_t)node * 64 + k0 + seg * 8 + 4];
            }
            ushort4 o0, o1;
            o0.x = f2bf(v0.x); o0.y = f2bf(v0.y); o0.z = f2bf(v0.z); o0.w = f2bf(v0.w);
            o1.x = f2bf(v1.x); o1.y = f2bf(v1.y); o1.z = f2bf(v1.z); o1.w = f2bf(v1.w);
            *(ushort4*)&ldsA[row * LDA + seg * 8] = o0;
            *(ushort4*)&ldsA[row * LDA + seg * 8 + 4] = o1;
        }
        __syncthreads();

        short8 a = *(const short8*)&ldsA[(wave * 16 + l16) * LDA + quad * 8];
#pragma unroll
        for (int nb = 0; nb < 4; nb++) {
            short8 bw;
#pragma unroll
            for (int j = 0; j < 8; j++)
                bw[j] = (short)f2bf(Wp[(size_t)(k0 + quad * 8 + j) * 64 + nb * 16 + l16]);
            aP[nb] = __builtin_amdgcn_mfma_f32_16x16x32_bf16(a, bw, aP[nb], 0, 0, 0);
#pragma unroll
            for (int j = 0; j < 8; j++)
                bw[j] = (short)f2bf(Wl1[(size_t)(k0 + quad * 8 + j) * 64 + nb * 16 + l16]);
            aY[nb] = __builtin_amdgcn_mfma_f32_16x16x32_bf16(a, bw, aY[nb], 0, 0, 0);
#pragma unroll
            for (int j = 0; j < 8; j++)
                bw[j] = (short)f2bf(Wr1[(size_t)(k0 + quad * 8 + j) * 64 + nb * 16 + l16]);
            aR[nb] = __builtin_amdgcn_mfma_f32_16x16x32_bf16(a, bw, aR[nb], 0, 0, 0);
        }
    }

#pragma unroll
    for (int nb = 0; nb < 4; nb++) {
        int ncol = nb * 16 + l16;
        float bv = bp[ncol];
#pragma unroll
        for (int r = 0; r < 4; r++) {
            int node = node0 + wave * 16 + quad * 4 + r;
            if (node >= N_NODES) continue;
            ushort xp = f2bf(fmaxf(aP[nb][r] + bv, 0.f));
            feats[(size_t)node * 256 + ncol] = xp;            // root operand for h2/h3
            g1in[(size_t)node * 128 + 64 + ncol] = xp;        // gather #1 input (x_p half)
            g1in[(size_t)node * 128 + ncol] = f2bf(aY[nb][r]); // y1 half
            r1[(size_t)node * 64 + ncol] = f2bf(aR[nb][r]);   // h1 root partial
        }
    }
}

// fused: [ELL fill (1 thr/edge, churny but hidden) | GEMM1 | weight swizzles]
__global__ __launch_bounds__(256) void k1_mega(
    const int* __restrict__ src, const int* __restrict__ dst, int E,
    int* __restrict__ fillc, ushort* __restrict__ ell,
    const float* __restrict__ x,
    const float* __restrict__ Wp, const float* __restrict__ bp,
    const float* __restrict__ Wl1, const float* __restrict__ Wr1,
    ushort* __restrict__ feats, ushort* __restrict__ g1in, ushort* __restrict__ r1,
    const float* __restrict__ Wl2, ushort* __restrict__ zl2,
    const float* __restrict__ Wr2, ushort* __restrict__ zr2,
    const float* __restrict__ Wl3, ushort* __restrict__ zl3,
    const float* __restrict__ Wr3, ushort* __restrict__ zr3,
    int NF, int NG)
{
    __shared__ ushort ldsA[64 * 40];
    int b = blockIdx.x, tid = threadIdx.x;
    if (b < NF) {                       // ELL fill: max TLP
        int t = b * 256 + tid;
        if (t < E) {
            int d = dst[t], s = src[t];
            int p = atomicAdd(&fillc[d], 1);
            if (p < ELLW) ell[(size_t)d * ELLW + p] = (ushort)s;
        }
        return;
    }
    b -= NF;
    if (b < NG) { gemm1_body(b, x, Wp, bp, Wl1, Wr1, feats, g1in, r1, ldsA); return; }
    b -= NG;
    if      (b < 8)  swz_body(Wl2, zl2, 128, (b - 0) * 256 + tid);
    else if (b < 16) swz_body(Wr2, zr2, 128, (b - 8) * 256 + tid);
    else if (b < 32) swz_body(Wl3, zl3, 128, (b - 16) * 256 + tid);
    else             swz_body(Wr3, zr3, 128, (b - 32) * 256 + tid);
}

// ---------------- gathers (mean, bf16, 1 node/wave, unroll-4) ----------------

// 128-col gather with split destinations: cols 0:64 -> dA, cols 64:128 -> dB
__global__ __launch_bounds__(256) void gather_split_k(const int* __restrict__ fillc,
                                                      const ushort* __restrict__ ell,
                                                      const ushort* __restrict__ in, int sin,
                                                      ushort* __restrict__ dA, int sA,
                                                      ushort* __restrict__ dB, int sB) {
    int node = blockIdx.x * 4 + (threadIdx.x >> 6);
    if (node >= N_NODES) return;
    int lane = threadIdx.x & 63;
    int sub = lane >> 4, c = lane & 15;
    int n = fillc[node]; int nc = (n > ELLW) ? ELLW : n;
    const ushort* base = ell + (size_t)node * ELLW;
    float a[8];
#pragma unroll
    for (int j = 0; j < 8; j++) a[j] = 0.f;

    int i = sub;
    for (; i + 12 < nc; i += 16) {
        uint4 u0 = *(const uint4*)&in[(size_t)base[i] * sin + 8 * c];
        uint4 u1 = *(const uint4*)&in[(size_t)base[i + 4] * sin + 8 * c];
        uint4 u2 = *(const uint4*)&in[(size_t)base[i + 8] * sin + 8 * c];
        uint4 u3 = *(const uint4*)&in[(size_t)base[i + 12] * sin + 8 * c];
        a[0] += (bflo(u0.x) + bflo(u1.x)) + (bflo(u2.x) + bflo(u3.x));
        a[1] += (bfhi(u0.x) + bfhi(u1.x)) + (bfhi(u2.x) + bfhi(u3.x));
        a[2] += (bflo(u0.y) + bflo(u1.y)) + (bflo(u2.y) + bflo(u3.y));
        a[3] += (bfhi(u0.y) + bfhi(u1.y)) + (bfhi(u2.y) + bfhi(u3.y));
        a[4] += (bflo(u0.z) + bflo(u1.z)) + (bflo(u2.z) + bflo(u3.z));
        a[5] += (bfhi(u0.z) + bfhi(u1.z)) + (bfhi(u2.z) + bfhi(u3.z));
        a[6] += (bflo(u0.w) + bflo(u1.w)) + (bflo(u2.w) + bflo(u3.w));
        a[7] += (bfhi(u0.w) + bfhi(u1.w)) + (bfhi(u2.w) + bfhi(u3.w));
    }
    for (; i < nc; i += 4) {
        uint4 u0 = *(const uint4*)&in[(size_t)base[i] * sin + 8 * c];
        a[0] += bflo(u0.x);  a[1] += bfhi(u0.x);
        a[2] += bflo(u0.y);  a[3] += bfhi(u0.y);
        a[4] += bflo(u0.z);  a[5] += bfhi(u0.z);
        a[6] += bflo(u0.w);  a[7] += bfhi(u0.w);
    }
#pragma unroll
    for (int j = 0; j < 8; j++) {
        a[j] += __shfl_xor(a[j], 16);
        a[j] += __shfl_xor(a[j], 32);
    }
    if (sub == 0) {
        float iv = 1.0f / fmaxf((float)n, 1.0f);
        uint4 r;
        r.x = pack2(a[0] * iv, a[1] * iv);
        r.y = pack2(a[2] * iv, a[3] * iv);
        r.z = pack2(a[4] * iv, a[5] * iv);
        r.w = pack2(a[6] * iv, a[7] * iv);
        if (c < 8) *(uint4*)&dA[(size_t)node * sA + 8 * c] = r;
        else       *(uint4*)&dB[(size_t)node * sB + 8 * (c - 8)] = r;
    }
}

// 64-col gather; 2 nodes/wave
__global__ __launch_bounds__(256) void gather64_k(const int* __restrict__ fillc,
                                                  const ushort* __restrict__ ell,
                                                  const ushort* __restrict__ in, int sin,
                                                  ushort* __restrict__ out, int sout) {
    int wid = blockIdx.x * 4 + (threadIdx.x >> 6);
    int lane = threadIdx.x & 63;
    int half = lane >> 5;
    int node = wid * 2 + half;
    if (node >= N_NODES) return;
    int l32 = lane & 31;
    int sub = l32 >> 3, c = l32 & 7;
    int n = fillc[node]; int nc = (n > ELLW) ? ELLW : n;
    const ushort* base = ell + (size_t)node * ELLW;
    float a[8];
#pragma unroll
    for (int j = 0; j < 8; j++) a[j] = 0.f;

    int i = sub;
    for (; i + 12 < nc; i += 16) {
        uint4 u0 = *(const uint4*)&in[(size_t)base[i] * sin + 8 * c];
        uint4 u1 = *(const uint4*)&in[(size_t)base[i + 4] * sin + 8 * c];
        uint4 u2 = *(const uint4*)&in[(size_t)base[i + 8] * sin + 8 * c];
        uint4 u3 = *(const uint4*)&in[(size_t)base[i + 12] * sin + 8 * c];
        a[0] += (bflo(u0.x) + bflo(u1.x)) + (bflo(u2.x) + bflo(u3.x));
        a[1] += (bfhi(u0.x) + bfhi(u1.x)) + (bfhi(u2.x) + bfhi(u3.x));
        a[2] += (bflo(u0.y) + bflo(u1.y)) + (bflo(u2.y) + bflo(u3.y));
        a[3] += (bfhi(u0.y) + bfhi(u1.y)) + (bfhi(u2.y) + bfhi(u3.y));
        a[4] += (bflo(u0.z) + bflo(u1.z)) + (bflo(u2.z) + bflo(u3.z));
        a[5] += (bfhi(u0.z) + bfhi(u1.z)) + (bfhi(u2.z) + bfhi(u3.z));
        a[6] += (bflo(u0.w) + bflo(u1.w)) + (bflo(u2.w) + bflo(u3.w));
        a[7] += (bfhi(u0.w) + bfhi(u1.w)) + (bfhi(u2.w) + bfhi(u3.w));
    }
    for (; i < nc; i += 4) {
        uint4 u0 = *(const uint4*)&in[(size_t)base[i] * sin + 8 * c];
        a[0] += bflo(u0.x);  a[1] += bfhi(u0.x);
        a[2] += bflo(u0.y);  a[3] += bfhi(u0.y);
        a[4] += bflo(u0.z);  a[5] += bfhi(u0.z);
        a[6] += bflo(u0.w);  a[7] += bfhi(u0.w);
    }
#pragma unroll
    for (int j = 0; j < 8; j++) {
        a[j] += __shfl_xor(a[j], 8);
        a[j] += __shfl_xor(a[j], 16);
    }
    if (sub == 0) {
        float iv = 1.0f / fmaxf((float)n, 1.0f);
        uint4 r;
        r.x = pack2(a[0] * iv, a[1] * iv);
        r.y = pack2(a[2] * iv, a[3] * iv);
        r.z = pack2(a[4] * iv, a[5] * iv);
        r.w = pack2(a[6] * iv, a[7] * iv);
        *(uint4*)&out[(size_t)node * sout + 8 * c] = r;
    }
}

// ---------------- h1 elementwise: h1 = relu(aggY1 + r1 + bl1) ----------------
__global__ __launch_bounds__(256) void h1ew_k(const ushort* __restrict__ aggY1,
                                              const ushort* __restrict__ r1,
                                              const float* __restrict__ bl1,
                                              ushort* __restrict__ feats) {
    int t = blockIdx.x * 256 + threadIdx.x;
    if (t >= N_NODES * 8) return;
    int node = t >> 3, c0 = (t & 7) * 8;
    uint4 a = *(const uint4*)&aggY1[(size_t)node * 64 + c0];
    uint4 b = *(const uint4*)&r1[(size_t)node * 64 + c0];
    float4 b0 = *(const float4*)&bl1[c0];
    float4 b1 = *(const float4*)&bl1[c0 + 4];
    uint4 o;
    o.x = pack2(fmaxf(bflo(a.x) + bflo(b.x) + b0.x, 0.f),
                fmaxf(bfhi(a.x) + bfhi(b.x) + b0.y, 0.f));
    o.y = pack2(fmaxf(bflo(a.y) + bflo(b.y) + b0.z, 0.f),
                fmaxf(bfhi(a.y) + bfhi(b.y) + b0.w, 0.f));
    o.z = pack2(fmaxf(bflo(a.z) + bflo(b.z) + b1.x, 0.f),
                fmaxf(bfhi(a.z) + bfhi(b.z) + b1.y, 0.f));
    o.w = pack2(fmaxf(bflo(a.w) + bflo(b.w) + b1.z, 0.f),
                fmaxf(bfhi(a.w) + bfhi(b.w) + b1.w, 0.f));
    *(uint4*)&feats[(size_t)node * 256 + 64 + c0] = o;
}

// ---------------- MFMA GEMM (two-phase; unchanged) ----------------
template <int O, bool OUT_BF16>
__global__ __launch_bounds__(256) void mfma_gemm_k(
    const ushort* __restrict__ A1, int s1, int K1, const ushort* __restrict__ Wz1,
    const ushort* __restrict__ A2, int s2, int K2, const ushort* __restrict__ Wz2,
    const float* __restrict__ bias, void* __restrict__ outp, int so, int ocol)
{
    constexpr int NB = O / 16;
    constexpr int LDA = 40;
    __shared__ ushort ldsA[64 * LDA];

    const int tid = threadIdx.x;
    const int wave = tid >> 6, lane = tid & 63;
    const int quad = lane >> 4, l16 = lane & 15;
    const int node0 = blockIdx.x * 64;

    floatx4 acc[NB];
#pragma unroll
    for (int nb = 0; nb < NB; nb++) acc[nb] = (floatx4){0, 0, 0, 0};

#pragma unroll 1
    for (int phase = 0; phase < 2; ++phase) {
        const ushort* A = phase ? A2 : A1;
        const ushort* Wz = phase ? Wz2 : Wz1;
        const int K = phase ? K2 : K1;
        const int sA = phase ? s2 : s1;

#pragma unroll 1
        for (int k0 = 0; k0 < K; k0 += 32) {
            __syncthreads();
            {
                int row = tid >> 2, seg = tid & 3;
                int node = node0 + row;
                uint4 v = {0, 0, 0, 0};
                if (node < N_NODES)
                    v = *(const uint4*)&A[(size_t)node * sA + k0 + seg * 8];
                *(uint4*)&ldsA[row * LDA + seg * 8] = v;
            }
            __syncthreads();

            short8 a = *(const short8*)&ldsA[(wave * 16 + l16) * LDA + quad * 8];
            const short8* bz = (const short8*)Wz + (size_t)(k0 >> 5) * NB * 64;
#pragma unroll
            for (int nb = 0; nb < NB; nb++) {
                short8 b = bz[nb * 64 + lane];
                acc[nb] = __builtin_amdgcn_mfma_f32_16x16x32_bf16(a, b, acc[nb], 0, 0, 0);
            }
        }
    }

#pragma unroll
    for (int nb = 0; nb < NB; nb++) {
        int ncol = nb * 16 + l16;
        float bv = bias[ncol];
#pragma unroll
        for (int r = 0; r < 4; r++) {
            int node = node0 + wave * 16 + quad * 4 + r;
            if (node >= N_NODES) continue;
            float v = fmaxf(acc[nb][r] + bv, 0.f);
            if (OUT_BF16)
                ((ushort*)outp)[(size_t)node * so + ocol + ncol] = f2bf(v);
            else
                ((float*)outp)[(size_t)node * so + ocol + ncol] = v;
        }
    }
}

// ---------------- launch ----------------

extern "C" void kernel_launch(void* const* d_in, const int* in_sizes, int n_in,
                              void* d_out, int out_size, void* d_ws, size_t ws_size,
                              hipStream_t stream) {
    const float* x   = (const float*)d_in[0];
    const int*   ei  = (const int*)d_in[1];
    const float* Wp  = (const float*)d_in[2];
    const float* bp  = (const float*)d_in[3];
    const float* Wl1 = (const float*)d_in[4];
    const float* bl1 = (const float*)d_in[5];
    const float* Wr1 = (const float*)d_in[6];
    const float* Wl2 = (const float*)d_in[7];
    const float* bl2 = (const float*)d_in[8];
    const float* Wr2 = (const float*)d_in[9];
    const float* Wl3 = (const float*)d_in[10];
    const float* bl3 = (const float*)d_in[11];
    const float* Wr3 = (const float*)d_in[12];

    const int E = in_sizes[1] / 2;
    const int N = N_NODES;
    const int* src = ei;
    const int* dst = ei + E;

    // ---- workspace carve-up (all offsets 16B-aligned) ----
    char* p = (char*)d_ws;
    ushort* feats = (ushort*)p;  p += (size_t)N * 256 * 2;  // [x_p | h1 | h2]
    ushort* g1in  = (ushort*)p;  p += (size_t)N * 128 * 2;  // [y1 | x_p]
    ushort* aggY1 = (ushort*)p;  p += (size_t)N * 64 * 2;   // mean(y1)
    ushort* aggf  = (ushort*)p;  p += (size_t)N * 256 * 2;  // [agg_xp|agg_h1|agg_h2]
    ushort* r1    = (ushort*)p;  p += (size_t)N * 64 * 2;   // x@Wr1
    int* fillc    = (int*)p;     p += (size_t)N * 4;
    ushort* ell   = (ushort*)p;  p += (size_t)N * ELLW * 2;
    ushort* zl2   = (ushort*)p;  p += 128 * 128 * 2;
    ushort* zr2   = (ushort*)p;  p += 128 * 128 * 2;
    ushort* zl3   = (ushort*)p;  p += 256 * 128 * 2;
    ushort* zr3   = (ushort*)p;  p += 256 * 128 * 2;

    hipMemsetAsync(fillc, 0, (size_t)N * sizeof(int), stream);

    const int NF = (E + 255) / 256;       // 3125 fill blocks
    const int NG = (N + 63) / 64;         // 782 gemm blocks

    // K1: fill + [x_p, y1, r1] GEMMs + swizzles (zl2, zr2, zl3, zr3)
    k1_mega<<<NF + NG + 48, 256, 0, stream>>>(
        src, dst, E, fillc, ell, x, Wp, bp, Wl1, Wr1, feats, g1in, r1,
        Wl2, zl2, Wr2, zr2, Wl3, zl3, Wr3, zr3, NF, NG);

    // gather #1: mean([y1|x_p]) -> aggY1 (cols 0:64) and aggf[:,0:64] (x_p half)
    gather_split_k<<<(N + 3) / 4, 256, 0, stream>>>(
        fillc, ell, g1in, 128, aggY1, 64, aggf, 256);

    // h1 = relu(aggY1 + r1 + bl1) -> feats[:,64:128]   (elementwise)
    h1ew_k<<<(N * 8 + 255) / 256, 256, 0, stream>>>(aggY1, r1, bl1, feats);

    // gather #2: mean(h1) -> aggf[:,64:128]
    gather64_k<<<(N + 7) / 8, 256, 0, stream>>>(fillc, ell, feats + 64, 256, aggf + 64, 256);

    // h2 = relu(aggf[:,0:128]@Wl2 + feats[:,0:128]@Wr2 + bl2) -> feats[:,128:256]
    mfma_gemm_k<128, true><<<NG, 256, 0, stream>>>(
        aggf, 256, 128, zl2, feats, 256, 128, zr2, bl2, feats, 256, 128);

    // gather #3: mean(h2) -> aggf[:,128:256]
    gather_split_k<<<(N + 3) / 4, 256, 0, stream>>>(
        fillc, ell, feats + 128, 256, aggf + 128, 256, aggf + 192, 256);

    // h3 = relu(aggf@Wl3 + feats@Wr3 + bl3) -> d_out (fp32)
    mfma_gemm_k<128, false><<<NG, 256, 0, stream>>>(
        aggf, 256, 256, zl3, feats, 256, 256, zr3, bl3, (float*)d_out, 128, 0);
}